// Round 6
// baseline (447.491 us; speedup 1.0000x reference)
//
#include <hip/hip_runtime.h>
#include <hip/hip_bf16.h>

typedef __attribute__((ext_vector_type(4))) float f32x4;
typedef __attribute__((ext_vector_type(8))) short bf16x8;

#define BM 256
#define BN 256
#define BK 32
#define KDIM 512
#define NT 16   // 512/32 K-tiles

// fp32 -> packed 2x bf16 (RNE); compiler emits v_cvt_pk_bf16_f32.
__device__ __forceinline__ unsigned int bfpack(float a, float b) {
  __hip_bfloat162 h = __float22bfloat162_rn(float2{a, b});
  union { __hip_bfloat162 h2; unsigned int u; } c;
  c.h2 = h;
  return c.u;
}

typedef __attribute__((address_space(1))) const unsigned int gas_u32;
typedef __attribute__((address_space(3))) unsigned int las_u32;

// Direct global->LDS DMA, 16B per lane. LDS dest = wave-uniform base + lane*16.
__device__ __forceinline__ void gload16(const float* g, float* l) {
  __builtin_amdgcn_global_load_lds((gas_u32*)(const void*)g, (las_u32*)(void*)l, 16, 0, 0);
}

// Read one MFMA A/B fragment (8 fp32 -> 8 bf16) from the swizzled fp32 tile.
// LDS granule (row, g) holds global granule g ^ (row&7); to get global
// granules {fg, fg+1} read LDS granules {fg^s, (fg+1)^s}.
__device__ __forceinline__ bf16x8 readfrag(const float* buf, int row, int fg) {
  const int s = row & 7;
  const f32x4 lo = *(const f32x4*)(buf + row * BK + ((fg ^ s) << 2));
  const f32x4 hi = *(const f32x4*)(buf + row * BK + (((fg + 1) ^ s) << 2));
  union { bf16x8 v; unsigned int u[4]; } r;
  r.u[0] = bfpack(lo[0], lo[1]);
  r.u[1] = bfpack(lo[2], lo[3]);
  r.u[2] = bfpack(hi[0], hi[1]);
  r.u[3] = bfpack(hi[2], hi[3]);
  return r.v;
}

__device__ __forceinline__ void hw_barrier() {
  asm volatile("s_barrier" ::: "memory");
}

__launch_bounds__(512, 2)
__global__ void moe_grouped_gemm(const float* __restrict__ A,
                                 const float* __restrict__ W,
                                 float* __restrict__ C) {
  // fp32 tiles, double-buffered, granule-swizzled: 2*(256*32)*4B*2 = 128 KiB.
  __shared__ float As[2][BM * BK];
  __shared__ float Bs[2][BN * BK];

  const int tid  = threadIdx.x;
  const int lane = tid & 63;
  const int wid  = tid >> 6;     // 8 waves
  const int wm   = wid >> 2;     // 0..1 (128-row half)
  const int wn   = wid & 3;      // 0..3 (64-col strip)

  // XCD map: b&7 = XCD = expert; n fastest (nt-pairs share A-panel in L2),
  // expert's 1 MB weight stays L2-resident per XCD.
  const int bidx = blockIdx.x;
  const int e  = bidx & 7;
  const int tt = bidx >> 3;      // 0..255
  const int mt = tt >> 1;        // 128 m-tiles
  const int nt = tt & 1;         // 2 n-tiles

  const size_t mBase = (size_t)e * 32768 + (size_t)mt * BM;
  const int    nBase = nt * BN;

  const float* Ap = A + mBase * KDIM;
  const float* Wp = W + ((size_t)e * 512 + nBase) * KDIM;

  // staging lane geometry: one gload16 covers 8 rows x 8 granules (1 KiB)
  const int srow = lane >> 3;    // row within 8-row chunk
  const int sg   = lane & 7;     // 16B granule within row
  // fragment lane geometry
  const int fr = lane & 15;
  const int fg = (lane >> 4) << 1;   // granule pair base: 0,2,4,6

  // Stage one K-tile (A + B) into buffer `buf`: 4+4 gload_lds per wave.
  // Source granule pre-swizzled so LDS(r,g) = global(r, g^(r&7)).
#define STAGE(tile, buf)                                                     \
  {                                                                          \
    const int tcol_ = (tile) * BK;                                           \
    _Pragma("unroll")                                                        \
    for (int i_ = 0; i_ < 4; ++i_) {                                         \
      const int row_ = wid * 32 + i_ * 8 + srow;                             \
      const int gc_  = tcol_ + ((sg ^ (row_ & 7)) << 2);                     \
      gload16(Ap + (size_t)row_ * KDIM + gc_, &As[buf][(wid * 32 + i_ * 8) * BK]); \
      gload16(Wp + (size_t)row_ * KDIM + gc_, &Bs[buf][(wid * 32 + i_ * 8) * BK]); \
    }                                                                        \
  }

  f32x4 acc[8][4];
  #pragma unroll
  for (int i = 0; i < 8; ++i)
    #pragma unroll
    for (int j = 0; j < 4; ++j)
      acc[i][j] = (f32x4){0.f, 0.f, 0.f, 0.f};

  // ---- prologue: DMA tiles 0 and 1; wait tile 0 only (tile 1 stays in flight)
  STAGE(0, 0);
  STAGE(1, 1);
  asm volatile("s_waitcnt vmcnt(8)" ::: "memory");
  hw_barrier();

  for (int t = 0; t < NT; ++t) {
    const int bb = t & 1;
    const float* Ab = &As[bb][0];
    const float* Bb = &Bs[bb][0];

    // ---- phase 0: issue next tile's DMA, read B + A(lo) frags, MFMA ----
    if (t >= 1 && t + 1 < NT) STAGE(t + 1, bb ^ 1);

    bf16x8 bfB[4];
    #pragma unroll
    for (int ni = 0; ni < 4; ++ni)
      bfB[ni] = readfrag(Bb, wn * 64 + ni * 16 + fr, fg);
    bf16x8 bfA[4];
    #pragma unroll
    for (int mi = 0; mi < 4; ++mi)
      bfA[mi] = readfrag(Ab, wm * 128 + mi * 16 + fr, fg);

    hw_barrier();
    __builtin_amdgcn_s_setprio(1);
    #pragma unroll
    for (int mi = 0; mi < 4; ++mi)
      #pragma unroll
      for (int ni = 0; ni < 4; ++ni)
        acc[mi][ni] = __builtin_amdgcn_mfma_f32_16x16x32_bf16(bfA[mi], bfB[ni], acc[mi][ni], 0, 0, 0);
    __builtin_amdgcn_s_setprio(0);
    hw_barrier();

    // ---- phase 1: read A(hi) frags, MFMA; drain next tile's DMA at the end ----
    #pragma unroll
    for (int mi = 0; mi < 4; ++mi)
      bfA[mi] = readfrag(Ab, wm * 128 + (mi + 4) * 16 + fr, fg);

    hw_barrier();
    __builtin_amdgcn_s_setprio(1);
    #pragma unroll
    for (int mi = 0; mi < 4; ++mi)
      #pragma unroll
      for (int ni = 0; ni < 4; ++ni)
        acc[mi + 4][ni] = __builtin_amdgcn_mfma_f32_16x16x32_bf16(bfA[mi], bfB[ni], acc[mi + 4][ni], 0, 0, 0);
    __builtin_amdgcn_s_setprio(0);

    if (t + 1 < NT) asm volatile("s_waitcnt vmcnt(0)" ::: "memory");
    hw_barrier();   // entry barrier of tile t+1: buffer valid for all waves
  }

  // ---- epilogue: C/D layout row = (lane>>4)*4 + reg, col = lane&15 ----
  #pragma unroll
  for (int mi = 0; mi < 8; ++mi) {
    #pragma unroll
    for (int reg = 0; reg < 4; ++reg) {
      const int r = wm * 128 + mi * 16 + ((lane >> 4) << 2) + reg;
      float* rowp = C + (mBase + r) * 512 + nBase + wn * 64 + (lane & 15);
      #pragma unroll
      for (int ni = 0; ni < 4; ++ni)
        __builtin_nontemporal_store(acc[mi][ni][reg], rowp + ni * 16);
    }
  }
#undef STAGE
}

extern "C" void kernel_launch(void* const* d_in, const int* in_sizes, int n_in,
                              void* d_out, int out_size, void* d_ws, size_t ws_size,
                              hipStream_t stream) {
  const float* inputs = (const float*)d_in[0];   // [262144, 512] fp32
  const float* weight = (const float*)d_in[1];   // [8, 512, 512] fp32
  float* out = (float*)d_out;                    // [262144, 512] fp32
  (void)d_ws; (void)ws_size; (void)in_sizes; (void)n_in;

  moe_grouped_gemm<<<2048, 512, 0, stream>>>(inputs, weight, out);
}

// Round 7
// 342.149 us; speedup vs baseline: 1.3079x; 1.3079x over previous
//
#include <hip/hip_runtime.h>
#include <hip/hip_bf16.h>

typedef __attribute__((ext_vector_type(4))) float f32x4;
typedef __attribute__((ext_vector_type(8))) short bf16x8;

#define BM 256
#define BN 256
#define BK 32
#define KDIM 512
#define NT 16   // 512/32 K-tiles

// fp32 -> packed 2x bf16 (RNE); compiler emits v_cvt_pk_bf16_f32.
__device__ __forceinline__ unsigned int bfpack(float a, float b) {
  __hip_bfloat162 h = __float22bfloat162_rn(float2{a, b});
  union { __hip_bfloat162 h2; unsigned int u; } c;
  c.h2 = h;
  return c.u;
}

// 16B-granule XOR swizzle — verified 0 conflicts at this exact geometry
// (bf16 rows of 64B, b128 frag reads + 8B staging writes) in R3/R4/R5.
__device__ __forceinline__ int swz(int row, int col) {
  return col ^ (((row >> 1) & 3) << 3);
}

__device__ __forceinline__ void lgkm0() {
  asm volatile("s_waitcnt lgkmcnt(0)" ::: "memory");
}

__launch_bounds__(512, 2)
__global__ void moe_grouped_gemm(const float* __restrict__ A,
                                 const float* __restrict__ W,
                                 float* __restrict__ C) {
  // bf16 tiles, double buffered: 2*(256+256)*32*2B = 64 KiB LDS.
  __shared__ ushort As[2][BM][BK];
  __shared__ ushort Bs[2][BN][BK];

  const int tid  = threadIdx.x;
  const int lane = tid & 63;
  const int wid  = tid >> 6;     // 8 waves
  const int wm   = wid >> 2;     // 0..1 (128-row half)
  const int wn   = wid & 3;      // 0..3 (64-col strip)

  // XCD map: b&7 = XCD = expert; nt fastest (pairs share A-panel in L2).
  const int bidx = blockIdx.x;
  const int e  = bidx & 7;
  const int tt = bidx >> 3;      // 0..255
  const int mt = tt >> 1;        // 128 m-tiles
  const int nt = tt & 1;         // 2 n-tiles

  const size_t mBase = (size_t)e * 32768 + (size_t)mt * BM;
  const int    nBase = nt * BN;

  const float* Ap = A + mBase * KDIM;
  const float* Wp = W + ((size_t)e * 512 + nBase) * KDIM;

  // staging: 256 rows x 32 cols fp32 per matrix, 512 thr -> 4 float4/thread.
  const int srow = tid >> 1;            // 2 threads per row
  const int sc0  = (tid & 1) << 4;      // float col base: 0 or 16
  const float* Arow = Ap + (size_t)srow * KDIM + sc0;
  const float* Wrow = Wp + (size_t)srow * KDIM + sc0;

  // frag geometry
  const int fr    = lane & 15;
  const int kbase = (lane >> 4) << 3;

  f32x4 acc[8][4];
  #pragma unroll
  for (int i = 0; i < 8; ++i)
    #pragma unroll
    for (int j = 0; j < 4; ++j)
      acc[i][j] = (f32x4){0.f, 0.f, 0.f, 0.f};

  // Two register sets: set[p] holds loads for tiles == p (mod 2).
  float4 ra[2][4], rb[2][4];

  // Issue 8 global loads for tile T into set p (statically indexed via unroll).
#define ISSUE(T, p)                                                       \
  if ((T) < NT) {                                                         \
    _Pragma("unroll")                                                     \
    for (int i_ = 0; i_ < 4; ++i_) {                                      \
      ra[p][i_] = *(const float4*)(Arow + (T) * BK + i_ * 4);             \
      rb[p][i_] = *(const float4*)(Wrow + (T) * BK + i_ * 4);             \
    }                                                                     \
  }

  // Convert + write tile T (set p) into LDS buffer (T&1). Compiler places
  // counted vmcnt here (8 newer loads in flight -> vmcnt(8..15), never 0).
#define CVTWRITE(T, p)                                                    \
  if ((T) < NT) {                                                         \
    _Pragma("unroll")                                                     \
    for (int i_ = 0; i_ < 4; ++i_) {                                      \
      const int c_ = sc0 + i_ * 4;                                        \
      const int s_ = swz(srow, c_);                                       \
      uint2 pa_, pb_;                                                     \
      pa_.x = bfpack(ra[p][i_].x, ra[p][i_].y);                           \
      pa_.y = bfpack(ra[p][i_].z, ra[p][i_].w);                           \
      pb_.x = bfpack(rb[p][i_].x, rb[p][i_].y);                           \
      pb_.y = bfpack(rb[p][i_].z, rb[p][i_].w);                           \
      *(uint2*)&As[(T) & 1][srow][s_] = pa_;                              \
      *(uint2*)&Bs[(T) & 1][srow][s_] = pb_;                              \
    }                                                                     \
  }

  // ---- prologue: issue t0,t1; cvt+write t0 (counted vmcnt); barrier ----
  ISSUE(0, 0);
  ISSUE(1, 1);
  CVTWRITE(0, 0);
  lgkm0();
  __builtin_amdgcn_s_barrier();

  // ---- main loop: fully unrolled, 2 phases/tile, 2 barriers/tile ----
  // ph0(t): issue t+2 | ds_read B + A-lo(cur) | MFMA mi0-3 | barrier
  // ph1(t): cvt+write t+1 -> buf[(t+1)&1] | ds_read A-hi(cur) | MFMA mi4-7
  //         | lgkm0 barrier  (writes visible before t+1 ph0 reads)
  // Hazards: W(nxt)@ph1(t) -> R(nxt)@ph0(t+1): 1 barrier (with lgkm0). R(cur)
  // last @ph1(t) -> W(cur)@ph1(t+1): 2 barriers. vmcnt never drained to 0.
  #pragma unroll
  for (int t = 0; t < NT; ++t) {
    const int cur = t & 1;

    // ---------------- phase 0 ----------------
    ISSUE(t + 2, cur);                      // set[cur] freed at ph1(t-1)
    __builtin_amdgcn_sched_barrier(0);

    bf16x8 bfB[4];
    #pragma unroll
    for (int ni = 0; ni < 4; ++ni) {
      const int rrow = wn * 64 + ni * 16 + fr;
      bfB[ni] = *(const bf16x8*)&Bs[cur][rrow][swz(rrow, kbase)];
    }
    bf16x8 bfA[4];
    #pragma unroll
    for (int mi = 0; mi < 4; ++mi) {
      const int arow = wm * 128 + mi * 16 + fr;
      bfA[mi] = *(const bf16x8*)&As[cur][arow][swz(arow, kbase)];
    }
    __builtin_amdgcn_s_setprio(1);
    #pragma unroll
    for (int mi = 0; mi < 4; ++mi)
      #pragma unroll
      for (int ni = 0; ni < 4; ++ni)
        acc[mi][ni] = __builtin_amdgcn_mfma_f32_16x16x32_bf16(bfA[mi], bfB[ni], acc[mi][ni], 0, 0, 0);
    __builtin_amdgcn_s_setprio(0);
    __builtin_amdgcn_s_barrier();

    // ---------------- phase 1 ----------------
    CVTWRITE(t + 1, (t + 1) & 1);           // counted vmcnt lands here
    __builtin_amdgcn_sched_barrier(0);

    #pragma unroll
    for (int mi = 0; mi < 4; ++mi) {
      const int arow = wm * 128 + (mi + 4) * 16 + fr;
      bfA[mi] = *(const bf16x8*)&As[cur][arow][swz(arow, kbase)];
    }
    __builtin_amdgcn_s_setprio(1);
    #pragma unroll
    for (int mi = 0; mi < 4; ++mi)
      #pragma unroll
      for (int ni = 0; ni < 4; ++ni)
        acc[mi + 4][ni] = __builtin_amdgcn_mfma_f32_16x16x32_bf16(bfA[mi], bfB[ni], acc[mi + 4][ni], 0, 0, 0);
    __builtin_amdgcn_s_setprio(0);

    lgkm0();                                 // ds_writes visible to all waves
    __builtin_amdgcn_s_barrier();
  }

  // ---- epilogue: C/D layout row = (lane>>4)*4 + reg, col = lane&15 ----
  #pragma unroll
  for (int mi = 0; mi < 8; ++mi) {
    #pragma unroll
    for (int reg = 0; reg < 4; ++reg) {
      const int r = wm * 128 + mi * 16 + ((lane >> 4) << 2) + reg;
      float* rowp = C + (mBase + r) * 512 + nBase + wn * 64 + (lane & 15);
      #pragma unroll
      for (int ni = 0; ni < 4; ++ni)
        __builtin_nontemporal_store(acc[mi][ni][reg], rowp + ni * 16);
    }
  }
#undef ISSUE
#undef CVTWRITE
}

extern "C" void kernel_launch(void* const* d_in, const int* in_sizes, int n_in,
                              void* d_out, int out_size, void* d_ws, size_t ws_size,
                              hipStream_t stream) {
  const float* inputs = (const float*)d_in[0];   // [262144, 512] fp32
  const float* weight = (const float*)d_in[1];   // [8, 512, 512] fp32
  float* out = (float*)d_out;                    // [262144, 512] fp32
  (void)d_ws; (void)ws_size; (void)in_sizes; (void)n_in;

  moe_grouped_gemm<<<2048, 512, 0, stream>>>(inputs, weight, out);
}